// Round 1
// baseline (249.508 us; speedup 1.0000x reference)
//
#include <hip/hip_runtime.h>
#include <hip/hip_bf16.h>
#include <hip/hip_fp16.h>

#define EMBED 1024
#define HEADS 16
#define HD 64
#define NBATCH 4
#define SEQ 2048
#define ROWS (NBATCH * SEQ)   // 8192
#define BANDW 5

typedef _Float16 f16;
typedef __attribute__((ext_vector_type(4))) _Float16 f16x4;
typedef __attribute__((ext_vector_type(8))) _Float16 f16x8;
typedef __attribute__((ext_vector_type(4))) float f32x4;

// ---------------- async global->LDS 16B copy ----------------
__device__ __forceinline__ void async_copy16(void* lds, const void* g) {
    __builtin_amdgcn_global_load_lds(
        (const __attribute__((address_space(1))) unsigned int*)g,
        (__attribute__((address_space(3))) unsigned int*)lds,
        16, 0, 0);
}

// ---------------- fp32 -> f16 conversion ----------------
__global__ __launch_bounds__(256) void cvt_f32_f16(const float* __restrict__ src,
                                                   f16* __restrict__ dst, int n) {
    int stride = gridDim.x * blockDim.x * 4;
    for (int i = (blockIdx.x * blockDim.x + threadIdx.x) * 4; i < n; i += stride) {
        float4 v = *(const float4*)(src + i);
        f16x4 o;
        o[0] = (f16)v.x; o[1] = (f16)v.y; o[2] = (f16)v.z; o[3] = (f16)v.w;
        *(f16x4*)(dst + i) = o;
    }
}

// ---------------- GEMM: C[M][N] = A[M][K] * B[N][K]^T ----------------
// A,B f16 row-major. OUTF32: C fp32 + bias; else C f16.
// 128x128 tile, BK=64, 256 threads (4 waves, 2x2 of 64x64), mfma 16x16x32 f16.
template <bool OUTF32>
__global__ __launch_bounds__(256) void gemm_bt(const f16* __restrict__ A,
                                               const f16* __restrict__ B,
                                               void* __restrict__ Cout,
                                               const float* __restrict__ bias,
                                               int M, int N, int K) {
    __shared__ __align__(16) f16 As[128 * 64];
    __shared__ __align__(16) f16 Bs[128 * 64];

    const int tid = threadIdx.x;
    const int w = tid >> 6;
    const int l = tid & 63;
    const int bm = blockIdx.y * 128;
    const int bn = blockIdx.x * 128;
    const int wm = (w >> 1) * 64;
    const int wn = (w & 1) * 64;

    const f32x4 vzero = {0.f, 0.f, 0.f, 0.f};
    f32x4 acc[4][4];
#pragma unroll
    for (int m = 0; m < 4; ++m)
#pragma unroll
        for (int n = 0; n < 4; ++n) acc[m][n] = vzero;

    const int nkt = K >> 6;
    for (int kt = 0; kt < nkt; ++kt) {
        const int k0 = kt << 6;
        // stage 128x64 A-tile and B-tile: 16 chunks of 1KB each per tile,
        // wave w stages chunks w*4..w*4+3 (wave-uniform LDS dest, per-lane src).
#pragma unroll
        for (int it = 0; it < 4; ++it) {
            const int ci = w * 4 + it;
            const int eoff = ci * 512 + l * 8;   // element offset in tile
            const int row = eoff >> 6;
            const int col = eoff & 63;
            async_copy16((char*)As + ci * 1024,
                         A + (size_t)(bm + row) * K + k0 + col);
            async_copy16((char*)Bs + ci * 1024,
                         B + (size_t)(bn + row) * K + k0 + col);
        }
        __syncthreads();   // compiler drains vmcnt before barrier

#pragma unroll
        for (int kk = 0; kk < 64; kk += 32) {
            f16x8 a[4], b[4];
#pragma unroll
            for (int m = 0; m < 4; ++m)
                a[m] = *(const f16x8*)&As[(wm + m * 16 + (l & 15)) * 64 + kk + (l >> 4) * 8];
#pragma unroll
            for (int n = 0; n < 4; ++n)
                b[n] = *(const f16x8*)&Bs[(wn + n * 16 + (l & 15)) * 64 + kk + (l >> 4) * 8];
#pragma unroll
            for (int m = 0; m < 4; ++m)
#pragma unroll
                for (int n = 0; n < 4; ++n)
                    acc[m][n] = __builtin_amdgcn_mfma_f32_16x16x32_f16(a[m], b[n], acc[m][n], 0, 0, 0);
        }
        __syncthreads();
    }

    // epilogue: C/D layout col = l&15, row = (l>>4)*4 + j
#pragma unroll
    for (int m = 0; m < 4; ++m) {
#pragma unroll
        for (int n = 0; n < 4; ++n) {
#pragma unroll
            for (int j = 0; j < 4; ++j) {
                const int row = bm + wm + m * 16 + (l >> 4) * 4 + j;
                const int col = bn + wn + n * 16 + (l & 15);
                const float v = acc[m][n][j];
                if (OUTF32) {
                    ((float*)Cout)[(size_t)row * N + col] = v + bias[col];
                } else {
                    ((f16*)Cout)[(size_t)row * N + col] = (f16)v;
                }
            }
        }
    }
}

// ---------------- banded attention ----------------
// one wave per (n, h, i); lane = d in [0,64). band |i-j| <= 5.
__global__ __launch_bounds__(256) void band_attn(const f16* __restrict__ Q,
                                                 const f16* __restrict__ K,
                                                 const f16* __restrict__ V,
                                                 f16* __restrict__ O) {
    const int gw = (blockIdx.x * 256 + threadIdx.x) >> 6;
    const int l = threadIdx.x & 63;
    const int i = gw & (SEQ - 1);
    const int nh = gw >> 11;
    const int h = nh & (HEADS - 1);
    const int n = nh >> 4;

    const size_t base = (size_t)n * SEQ * EMBED + (size_t)h * HD + l;
    const float q = (float)Q[base + (size_t)i * EMBED];

    float e[2 * BANDW + 1];
#pragma unroll
    for (int jj = 0; jj <= 2 * BANDW; ++jj) {
        const int j = i - BANDW + jj;
        const bool ok = (j >= 0) && (j < SEQ);
        const int jc = ok ? j : i;
        float p = q * (float)K[base + (size_t)jc * EMBED];
        p += __shfl_xor(p, 1);
        p += __shfl_xor(p, 2);
        p += __shfl_xor(p, 4);
        p += __shfl_xor(p, 8);
        p += __shfl_xor(p, 16);
        p += __shfl_xor(p, 32);
        e[jj] = ok ? p * 0.125f : -1e30f;
    }
    float mx = e[0];
#pragma unroll
    for (int jj = 1; jj <= 2 * BANDW; ++jj) mx = fmaxf(mx, e[jj]);
    float s = 0.f, o = 0.f;
#pragma unroll
    for (int jj = 0; jj <= 2 * BANDW; ++jj) {
        const float p = __expf(e[jj] - mx);   // invalid j -> exp(-inf) = 0
        s += p;
        int j = i - BANDW + jj;
        j = (j < 0) ? 0 : ((j >= SEQ) ? SEQ - 1 : j);
        o += p * (float)V[base + (size_t)j * EMBED];
    }
    O[base + (size_t)i * EMBED] = (f16)(o / s);
}

// ---------------- launch ----------------
extern "C" void kernel_launch(void* const* d_in, const int* in_sizes, int n_in,
                              void* d_out, int out_size, void* d_ws, size_t ws_size,
                              hipStream_t stream) {
    const float* values = (const float*)d_in[0];
    const float* keys   = (const float*)d_in[1];
    const float* query  = (const float*)d_in[2];
    // d_in[3] = mask: all-true in this problem; band mask applied in-kernel.
    const float* Wv = (const float*)d_in[4];
    const float* Wk = (const float*)d_in[5];
    const float* Wq = (const float*)d_in[6];
    const float* Wo = (const float*)d_in[7];
    const float* bo = (const float*)d_in[8];

    const size_t ME = (size_t)ROWS * EMBED;    // 8192*1024
    const size_t WE = (size_t)EMBED * EMBED;   // 1024*1024

    f16* xstage = (f16*)d_ws;          // staged f16 input (reused; also attn out)
    f16* Qp = xstage + ME;
    f16* Kp = Qp + ME;
    f16* Vp = Kp + ME;
    f16* wq = Vp + ME;
    f16* wk = wq + WE;
    f16* wv = wk + WE;
    f16* wo = wv + WE;

    const dim3 cblk(256);
    const dim3 ggrid(EMBED / 128, ROWS / 128);   // (8, 64)

    // weights -> f16
    cvt_f32_f16<<<1024, cblk, 0, stream>>>(Wq, wq, (int)WE);
    cvt_f32_f16<<<1024, cblk, 0, stream>>>(Wk, wk, (int)WE);
    cvt_f32_f16<<<1024, cblk, 0, stream>>>(Wv, wv, (int)WE);
    cvt_f32_f16<<<1024, cblk, 0, stream>>>(Wo, wo, (int)WE);

    // Q projection
    cvt_f32_f16<<<2048, cblk, 0, stream>>>(query, xstage, (int)ME);
    gemm_bt<false><<<ggrid, cblk, 0, stream>>>(xstage, wq, Qp, nullptr, ROWS, EMBED, EMBED);
    // K projection
    cvt_f32_f16<<<2048, cblk, 0, stream>>>(keys, xstage, (int)ME);
    gemm_bt<false><<<ggrid, cblk, 0, stream>>>(xstage, wk, Kp, nullptr, ROWS, EMBED, EMBED);
    // V projection
    cvt_f32_f16<<<2048, cblk, 0, stream>>>(values, xstage, (int)ME);
    gemm_bt<false><<<ggrid, cblk, 0, stream>>>(xstage, wv, Vp, nullptr, ROWS, EMBED, EMBED);

    // banded attention: 4*16*2048 waves
    band_attn<<<(NBATCH * HEADS * SEQ) / 4, cblk, 0, stream>>>(Qp, Kp, Vp, xstage);

    // output projection + bias -> fp32
    gemm_bt<true><<<ggrid, cblk, 0, stream>>>(xstage, wo, d_out, bo, ROWS, EMBED, EMBED);
}

// Round 2
// 173.822 us; speedup vs baseline: 1.4354x; 1.4354x over previous
//
#include <hip/hip_runtime.h>
#include <hip/hip_bf16.h>
#include <hip/hip_fp16.h>

#define EMBED 1024
#define HEADS 16
#define HD 64
#define NBATCH 4
#define SEQ 2048
#define ROWS (NBATCH * SEQ)   // 8192
#define BANDW 5

typedef _Float16 f16;
typedef __attribute__((ext_vector_type(2))) _Float16 f16x2;
typedef __attribute__((ext_vector_type(4))) _Float16 f16x4;
typedef __attribute__((ext_vector_type(8))) _Float16 f16x8;
typedef __attribute__((ext_vector_type(4))) float f32x4;

// ---------------- async global->LDS 16B copy ----------------
__device__ __forceinline__ void async_copy16(void* lds, const void* g) {
    __builtin_amdgcn_global_load_lds(
        (const __attribute__((address_space(1))) unsigned int*)g,
        (__attribute__((address_space(3))) unsigned int*)lds,
        16, 0, 0);
}

// ---------------- fp32 -> f16 conversion (8 elem/thread/iter) ----------------
__global__ __launch_bounds__(256) void cvt_f32_f16(const float* __restrict__ src,
                                                   f16* __restrict__ dst, int n) {
    const int stride = gridDim.x * 256 * 8;
    for (int i = (blockIdx.x * 256 + threadIdx.x) * 8; i < n; i += stride) {
        float4 a = *(const float4*)(src + i);
        float4 b = *(const float4*)(src + i + 4);
        f16x8 o;
        o[0] = (f16)a.x; o[1] = (f16)a.y; o[2] = (f16)a.z; o[3] = (f16)a.w;
        o[4] = (f16)b.x; o[5] = (f16)b.y; o[6] = (f16)b.z; o[7] = (f16)b.w;
        *(f16x8*)(dst + i) = o;
    }
}

// all 4 weight matrices in one launch; blockIdx.y picks the matrix.
__global__ __launch_bounds__(256) void cvt_w4(const float* __restrict__ w0,
                                              const float* __restrict__ w1,
                                              const float* __restrict__ w2,
                                              const float* __restrict__ w3,
                                              f16* __restrict__ dst) {
    const int wsel = blockIdx.y;
    const float* s = (wsel == 0) ? w0 : (wsel == 1) ? w1 : (wsel == 2) ? w2 : w3;
    f16* d = dst + (size_t)wsel * EMBED * EMBED;
    const int i = (blockIdx.x * 256 + threadIdx.x) * 8;
    float4 a = *(const float4*)(s + i);
    float4 b = *(const float4*)(s + i + 4);
    f16x8 o;
    o[0] = (f16)a.x; o[1] = (f16)a.y; o[2] = (f16)a.z; o[3] = (f16)a.w;
    o[4] = (f16)b.x; o[5] = (f16)b.y; o[6] = (f16)b.z; o[7] = (f16)b.w;
    *(f16x8*)(d + i) = o;
}

// ---------------- GEMM: C[M][N] = A[M][K] * B[N][K]^T ----------------
template <bool OUTF32>
__global__ __launch_bounds__(256) void gemm_bt(const f16* __restrict__ A,
                                               const f16* __restrict__ B,
                                               void* __restrict__ Cout,
                                               const float* __restrict__ bias,
                                               int M, int N, int K) {
    __shared__ __align__(16) f16 As[128 * 64];
    __shared__ __align__(16) f16 Bs[128 * 64];

    const int tid = threadIdx.x;
    const int w = tid >> 6;
    const int l = tid & 63;
    const int bm = blockIdx.y * 128;
    const int bn = blockIdx.x * 128;
    const int wm = (w >> 1) * 64;
    const int wn = (w & 1) * 64;

    const f32x4 vzero = {0.f, 0.f, 0.f, 0.f};
    f32x4 acc[4][4];
#pragma unroll
    for (int m = 0; m < 4; ++m)
#pragma unroll
        for (int n = 0; n < 4; ++n) acc[m][n] = vzero;

    const int nkt = K >> 6;
    for (int kt = 0; kt < nkt; ++kt) {
        const int k0 = kt << 6;
#pragma unroll
        for (int it = 0; it < 4; ++it) {
            const int ci = w * 4 + it;
            const int eoff = ci * 512 + l * 8;
            const int row = eoff >> 6;
            const int col = eoff & 63;
            async_copy16((char*)As + ci * 1024,
                         A + (size_t)(bm + row) * K + k0 + col);
            async_copy16((char*)Bs + ci * 1024,
                         B + (size_t)(bn + row) * K + k0 + col);
        }
        __syncthreads();

#pragma unroll
        for (int kk = 0; kk < 64; kk += 32) {
            f16x8 a[4], b[4];
#pragma unroll
            for (int m = 0; m < 4; ++m)
                a[m] = *(const f16x8*)&As[(wm + m * 16 + (l & 15)) * 64 + kk + (l >> 4) * 8];
#pragma unroll
            for (int n = 0; n < 4; ++n)
                b[n] = *(const f16x8*)&Bs[(wn + n * 16 + (l & 15)) * 64 + kk + (l >> 4) * 8];
#pragma unroll
            for (int m = 0; m < 4; ++m)
#pragma unroll
                for (int n = 0; n < 4; ++n)
                    acc[m][n] = __builtin_amdgcn_mfma_f32_16x16x32_f16(a[m], b[n], acc[m][n], 0, 0, 0);
        }
        __syncthreads();
    }

#pragma unroll
    for (int m = 0; m < 4; ++m) {
#pragma unroll
        for (int n = 0; n < 4; ++n) {
#pragma unroll
            for (int j = 0; j < 4; ++j) {
                const int row = bm + wm + m * 16 + (l >> 4) * 4 + j;
                const int col = bn + wn + n * 16 + (l & 15);
                const float v = acc[m][n][j];
                if (OUTF32) {
                    ((float*)Cout)[(size_t)row * N + col] = v + bias[col];
                } else {
                    ((f16*)Cout)[(size_t)row * N + col] = (f16)v;
                }
            }
        }
    }
}

// ---------------- banded attention v2: one THREAD per query ----------------
// block = 256 threads = 256 queries; K/V tile staged in LDS (row stride 68
// f16 = 136B -> 8B-aligned rows, bank class 2*lane mod 32 => free aliasing).
#define ATT_T 256
#define ATT_R (ATT_T + 2 * BANDW)   // 266 rows
#define ATT_S 68                    // f16 elements per LDS row

__global__ __launch_bounds__(256) void band_attn2(const f16* __restrict__ Q,
                                                  const f16* __restrict__ K,
                                                  const f16* __restrict__ V,
                                                  f16* __restrict__ O) {
    __shared__ __align__(16) f16 Ks[ATT_R * ATT_S];
    __shared__ __align__(16) f16 Vs[ATT_R * ATT_S];

    const int t = threadIdx.x;
    const int q0 = blockIdx.x * ATT_T;
    const int h = blockIdx.y;
    const int n = blockIdx.z;
    const size_t plane = (size_t)n * SEQ * EMBED + (size_t)h * HD;
    const int i = q0 + t;
    const size_t qbase = plane + (size_t)i * EMBED;

    // q row -> f32 registers (issued before staging barrier; lane-scattered
    // 16B loads, L2-resident since Q was just written)
    float qf[64];
#pragma unroll
    for (int c = 0; c < 8; ++c) {
        f16x8 v = *(const f16x8*)(Q + qbase + c * 8);
#pragma unroll
        for (int k = 0; k < 8; ++k) qf[c * 8 + k] = (float)v[k];
    }

    // stage K,V rows [q0-5, q0+260] (clamped; clamped rows masked later)
    for (int idx = t; idx < ATT_R * 8; idx += 256) {
        const int r = idx >> 3, c = idx & 7;
        int g = q0 - BANDW + r;
        g = g < 0 ? 0 : (g >= SEQ ? SEQ - 1 : g);
        const size_t src = plane + (size_t)g * EMBED + c * 8;
        f16x8 kv = *(const f16x8*)(K + src);
        f16x8 vv = *(const f16x8*)(V + src);
        f16* kd = &Ks[r * ATT_S + c * 8];
        f16* vd = &Vs[r * ATT_S + c * 8];
        f16x4 klo = {kv[0], kv[1], kv[2], kv[3]}, khi = {kv[4], kv[5], kv[6], kv[7]};
        f16x4 vlo = {vv[0], vv[1], vv[2], vv[3]}, vhi = {vv[4], vv[5], vv[6], vv[7]};
        *(f16x4*)kd = klo; *(f16x4*)(kd + 4) = khi;
        *(f16x4*)vd = vlo; *(f16x4*)(vd + 4) = vhi;
    }
    __syncthreads();

    // QK^T band: 11 lane-local dot products from LDS
    float e[2 * BANDW + 1];
#pragma unroll
    for (int jj = 0; jj <= 2 * BANDW; ++jj) {
        const int j = i - BANDW + jj;
        const f16* krow = &Ks[(t + jj) * ATT_S];
        float acc = 0.f;
#pragma unroll
        for (int c = 0; c < 16; ++c) {
            f16x4 kv = *(const f16x4*)(krow + c * 4);
            acc += qf[c * 4 + 0] * (float)kv[0];
            acc += qf[c * 4 + 1] * (float)kv[1];
            acc += qf[c * 4 + 2] * (float)kv[2];
            acc += qf[c * 4 + 3] * (float)kv[3];
        }
        e[jj] = (j >= 0 && j < SEQ) ? acc * 0.125f : -1e30f;
    }

    // scalar softmax (no cross-lane ops)
    float mx = e[0];
#pragma unroll
    for (int jj = 1; jj <= 2 * BANDW; ++jj) mx = fmaxf(mx, e[jj]);
    float p[2 * BANDW + 1];
    float s = 0.f;
#pragma unroll
    for (int jj = 0; jj <= 2 * BANDW; ++jj) {
        p[jj] = __expf(e[jj] - mx);
        s += p[jj];
    }
    const float inv = 1.f / s;
#pragma unroll
    for (int jj = 0; jj <= 2 * BANDW; ++jj) p[jj] *= inv;

    // PV in two d-halves of 32 (caps live f32 accumulators)
#pragma unroll
    for (int hh = 0; hh < 2; ++hh) {
        float o[32];
#pragma unroll
        for (int c = 0; c < 32; ++c) o[c] = 0.f;
#pragma unroll
        for (int jj = 0; jj <= 2 * BANDW; ++jj) {
            const f16* vrow = &Vs[(t + jj) * ATT_S + hh * 32];
            const float pj = p[jj];
#pragma unroll
            for (int c = 0; c < 8; ++c) {
                f16x4 vv = *(const f16x4*)(vrow + c * 4);
                o[c * 4 + 0] += pj * (float)vv[0];
                o[c * 4 + 1] += pj * (float)vv[1];
                o[c * 4 + 2] += pj * (float)vv[2];
                o[c * 4 + 3] += pj * (float)vv[3];
            }
        }
#pragma unroll
        for (int c = 0; c < 4; ++c) {
            f16x8 ov;
#pragma unroll
            for (int k = 0; k < 8; ++k) ov[k] = (f16)o[c * 8 + k];
            *(f16x8*)(O + qbase + hh * 32 + c * 8) = ov;
        }
    }
}

// ---------------- launch ----------------
extern "C" void kernel_launch(void* const* d_in, const int* in_sizes, int n_in,
                              void* d_out, int out_size, void* d_ws, size_t ws_size,
                              hipStream_t stream) {
    const float* values = (const float*)d_in[0];
    const float* keys   = (const float*)d_in[1];
    const float* query  = (const float*)d_in[2];
    // d_in[3] = mask: all-true in this problem; band mask applied in-kernel.
    const float* Wv = (const float*)d_in[4];
    const float* Wk = (const float*)d_in[5];
    const float* Wq = (const float*)d_in[6];
    const float* Wo = (const float*)d_in[7];
    const float* bo = (const float*)d_in[8];

    const size_t ME = (size_t)ROWS * EMBED;    // 8192*1024
    const size_t WE = (size_t)EMBED * EMBED;   // 1024*1024

    f16* xstage = (f16*)d_ws;          // staged f16 input (reused; also attn out)
    f16* Qp = xstage + ME;
    f16* Kp = Qp + ME;
    f16* Vp = Kp + ME;
    f16* wq = Vp + ME;                 // wq,wk,wv,wo contiguous
    f16* wk = wq + WE;
    f16* wv = wk + WE;
    f16* wo = wv + WE;

    const dim3 cblk(256);
    const dim3 ggrid(EMBED / 128, ROWS / 128);   // (8, 64)

    // all 4 weights -> f16 in one launch
    cvt_w4<<<dim3(WE / (256 * 8), 4), cblk, 0, stream>>>(Wq, Wk, Wv, Wo, wq);

    // Q projection
    cvt_f32_f16<<<2048, cblk, 0, stream>>>(query, xstage, (int)ME);
    gemm_bt<false><<<ggrid, cblk, 0, stream>>>(xstage, wq, Qp, nullptr, ROWS, EMBED, EMBED);
    // K projection
    cvt_f32_f16<<<2048, cblk, 0, stream>>>(keys, xstage, (int)ME);
    gemm_bt<false><<<ggrid, cblk, 0, stream>>>(xstage, wk, Kp, nullptr, ROWS, EMBED, EMBED);
    // V projection
    cvt_f32_f16<<<2048, cblk, 0, stream>>>(values, xstage, (int)ME);
    gemm_bt<false><<<ggrid, cblk, 0, stream>>>(xstage, wv, Vp, nullptr, ROWS, EMBED, EMBED);

    // banded attention: one thread per query
    band_attn2<<<dim3(SEQ / ATT_T, HEADS, NBATCH), cblk, 0, stream>>>(Qp, Kp, Vp, xstage);

    // output projection + bias -> fp32
    gemm_bt<true><<<ggrid, cblk, 0, stream>>>(xstage, wo, d_out, bo, ROWS, EMBED, EMBED);
}